// Round 6
// baseline (53.054 us; speedup 1.0000x reference)
//
#include <hip/hip_runtime.h>
#include <hip/hip_bf16.h>
#include <cmath>

#define B_SZ 4096
#define N_SZ 8192
#define D_SZ 256
#define EPS 1e-8f
// zn is stored as fp8 e4m3 scaled by 16 -> acc = 256*cos.
// exp(sim-2) with sim = 2*cos = acc/128:  exp2( acc*log2e/128 - 2*log2e )
#define EXPC 0.01127105500694503f      // log2(e)/128
#define EXPB -2.8853900817779268f      // -2*log2(e)

typedef __attribute__((ext_vector_type(4))) float f32x4;
typedef __attribute__((ext_vector_type(4))) int   i32x4;
typedef __attribute__((ext_vector_type(8))) int   i32x8;

__device__ __forceinline__ void dma16(const void* g, void* l) {
    __builtin_amdgcn_global_load_lds(
        (const __attribute__((address_space(1))) unsigned int*)g,
        (__attribute__((address_space(3))) unsigned int*)l, 16, 0, 0);
}

// fp8 k-segment-transposed panel layout (1 byte/elem):
//   byte(row,k) = (row>>6)*16384 + (k>>4)*1024 + (row&63)*16 + (k&15)
// panel = 64 rows x 256 k = 16 KB. An MFMA operand (32 fp8 = one MX k-block of
// 32, k=(lane>>4)*32+[0..31]) = two 16-B loads 1024 B apart; 16-lane phases
// read 256 contiguous bytes -> 2 lanes/bank-quad = conflict-free.

// ---- Kernel 1: norms + pos (fp32 exact) + fp8 ZN. One wave per pair (i,i+B). ----
__global__ __launch_bounds__(256) void prep_kernel(const float* __restrict__ zi,
                                                   const float* __restrict__ zj,
                                                   char* __restrict__ znb,
                                                   float* __restrict__ pos) {
    const int wave = threadIdx.x >> 6, lane = threadIdx.x & 63;
    const int i = blockIdx.x * 4 + wave;               // 0..B-1
    float4 a = reinterpret_cast<const float4*>(zi + (size_t)i * D_SZ)[lane];
    float4 b = reinterpret_cast<const float4*>(zj + (size_t)i * D_SZ)[lane];
    float ssa = a.x * a.x + a.y * a.y + a.z * a.z + a.w * a.w;
    float ssb = b.x * b.x + b.y * b.y + b.z * b.z + b.w * b.w;
    float dab = a.x * b.x + a.y * b.y + a.z * b.z + a.w * b.w;
    #pragma unroll
    for (int off = 32; off; off >>= 1) {
        ssa += __shfl_xor(ssa, off, 64);
        ssb += __shfl_xor(ssb, off, 64);
        dab += __shfl_xor(dab, off, 64);
    }
    const float invna = 1.0f / fmaxf(sqrtf(ssa), EPS);
    const float invnb = 1.0f / fmaxf(sqrtf(ssb), EPS);
    if (lane == 0) {
        float p = dab * invna * invnb * 2.0f;
        pos[i] = p;
        pos[i + B_SZ] = p;
    }
    // lane covers k = 4*lane .. 4*lane+3; seg = lane>>2, in-seg byte = (lane&3)*4.
    const float sa = invna * 16.0f, sb = invnb * 16.0f;
    const int koff = (lane >> 2) * 1024 + (lane & 3) * 4;
    {
        int pk = __builtin_amdgcn_cvt_pk_fp8_f32(a.x * sa, a.y * sa, 0, false);
        pk     = __builtin_amdgcn_cvt_pk_fp8_f32(a.z * sa, a.w * sa, pk, true);
        *reinterpret_cast<int*>(znb + (size_t)(i >> 6) * 16384 + koff + (i & 63) * 16) = pk;
    }
    {
        const int r = i + B_SZ;
        int pk = __builtin_amdgcn_cvt_pk_fp8_f32(b.x * sb, b.y * sb, 0, false);
        pk     = __builtin_amdgcn_cvt_pk_fp8_f32(b.z * sb, b.w * sb, pk, true);
        *reinterpret_cast<int*>(znb + (size_t)(r >> 6) * 16384 + koff + (r & 63) * 16) = pk;
    }
}

// ---- Kernel 2: fused fp8 K=128 MFMA sim-GEMM + fixed-base exp-sum ----
// Grid: 32 row-tiles x 32 j-chunks = 1024 blocks (4/CU), 256 thr (4 waves).
// Wave holds a 64-row fp8 A panel in regs (64 VGPRs); B panels staged 16 KB
// linear via global_load_lds, double-buffered. 128 MFMA (16x16x128) per wave.
__global__ __launch_bounds__(256, 2) void simlse_kernel(const char* __restrict__ znb,
                                                        float* __restrict__ partial) {
    __shared__ __attribute__((aligned(16))) char lds[2][16384];

    const int t = threadIdx.x;
    const int wave = t >> 6, lane = t & 63;
    const int rt = blockIdx.x >> 5;              // row tile 0..31 (256 rows)
    const int chunk = blockIdx.x & 31;           // j chunk 0..31 (256 cols)
    const int rl = lane & 15;                    // A-row / B-col within fragment
    const int kg = lane >> 4;                    // 32-elem k-block index
    const int i0 = (rt * 4 + wave) * 64;         // wave's first row

    // Linear 16 KB panel copy: wave stages 4 KB = 4 x 1 KB DMA.
    #define STAGE(BUF, JT)                                                        \
        {                                                                         \
            const char* gp = znb + (size_t)(chunk * 4 + (JT)) * 16384 +           \
                             wave * 4096 + lane * 16;                             \
            char* lp = (BUF) + wave * 4096;                                       \
            _Pragma("unroll")                                                     \
            for (int c = 0; c < 4; ++c) dma16(gp + c * 1024, lp + c * 1024);      \
        }

    STAGE(lds[0], 0);                            // issue tile-0 DMA first

    // A panel: 4 rowgroups x 2 k-chunks of 128; 8 dwords (32 fp8) per frag.
    const char* ap = znb + (size_t)(rt * 4 + wave) * 16384 + rl * 16;
    i32x8 afrag[4][2];
    #pragma unroll
    for (int g = 0; g < 4; ++g)
        #pragma unroll
        for (int kc = 0; kc < 2; ++kc) {
            i32x4 lo = *reinterpret_cast<const i32x4*>(
                ap + (kc * 8 + kg * 2) * 1024 + g * 256);
            i32x4 hi = *reinterpret_cast<const i32x4*>(
                ap + (kc * 8 + kg * 2 + 1) * 1024 + g * 256);
            afrag[g][kc] = __builtin_shufflevector(lo, hi, 0, 1, 2, 3, 4, 5, 6, 7);
        }

    float s_acc[4][4];
    #pragma unroll
    for (int g = 0; g < 4; ++g)
        #pragma unroll
        for (int r = 0; r < 4; ++r) s_acc[g][r] = 0.0f;

    #define COMPUTE(BUF)                                                          \
        {                                                                         \
            _Pragma("unroll")                                                     \
            for (int f = 0; f < 4; ++f) {                                         \
                f32x4 acc[4];                                                     \
                _Pragma("unroll")                                                 \
                for (int g = 0; g < 4; ++g) acc[g] = (f32x4){0.f, 0.f, 0.f, 0.f}; \
                _Pragma("unroll")                                                 \
                for (int kc = 0; kc < 2; ++kc) {                                  \
                    i32x4 blo = *reinterpret_cast<const i32x4*>(                  \
                        (BUF) + (kc * 8 + kg * 2) * 1024 + (f * 16 + rl) * 16);   \
                    i32x4 bhi = *reinterpret_cast<const i32x4*>(                  \
                        (BUF) + (kc * 8 + kg * 2 + 1) * 1024 + (f * 16 + rl) * 16); \
                    i32x8 bfrag = __builtin_shufflevector(blo, bhi,               \
                                                          0, 1, 2, 3, 4, 5, 6, 7); \
                    _Pragma("unroll")                                             \
                    for (int g = 0; g < 4; ++g)                                   \
                        asm volatile(                                             \
                            "v_mfma_f32_16x16x128_f8f6f4 %0, %1, %2, %0"          \
                            : "+v"(acc[g])                                        \
                            : "v"(afrag[g][kc]), "v"(bfrag));                     \
                }                                                                 \
                asm volatile("s_nop 7");  /* MFMA->VALU read hazard guard */      \
                _Pragma("unroll")                                                 \
                for (int g = 0; g < 4; ++g)                                       \
                    _Pragma("unroll")                                             \
                    for (int r = 0; r < 4; ++r)                                   \
                        s_acc[g][r] += __builtin_amdgcn_exp2f(                    \
                            fmaf(acc[g][r], EXPC, EXPB));                         \
            }                                                                     \
        }

    __syncthreads();                       // tile 0 landed
    for (int jt = 0; jt < 4; ++jt) {       // NO unroll: keep regalloc scope small
        if (jt < 3) STAGE(lds[(jt + 1) & 1], jt + 1);
        COMPUTE(lds[jt & 1]);
        __syncthreads();                   // next tile landed; cur reads done
    }

    // Sum over the 16 col-lanes (rl); rows i0 + g*16 + kg*4 + r.
    #pragma unroll
    for (int g = 0; g < 4; ++g)
        #pragma unroll
        for (int r = 0; r < 4; ++r) {
            float v = s_acc[g][r];
            #pragma unroll
            for (int off = 1; off < 16; off <<= 1) v += __shfl_xor(v, off, 64);
            if (rl == 0)
                partial[chunk * N_SZ + i0 + g * 16 + kg * 4 + r] = v;
        }
    #undef STAGE
    #undef COMPUTE
}

// ---- Kernel 3: per-row lse - pos, 32 block partials ----
__global__ __launch_bounds__(256) void rowsum_kernel(const float* __restrict__ partial,
                                                     const float* __restrict__ pos,
                                                     float* __restrict__ bpart) {
    const int row = blockIdx.x * 256 + threadIdx.x;
    float s = -1.0f;                       // remove diagonal exp(~0)=1
    #pragma unroll
    for (int c = 0; c < 32; ++c) s += partial[c * N_SZ + row];
    float acc = 2.0f + logf(s) - pos[row];
    #pragma unroll
    for (int off = 32; off; off >>= 1) acc += __shfl_xor(acc, off, 64);
    __shared__ float w[4];
    if ((threadIdx.x & 63) == 0) w[threadIdx.x >> 6] = acc;
    __syncthreads();
    if (threadIdx.x == 0) bpart[blockIdx.x] = w[0] + w[1] + w[2] + w[3];
}

__global__ __launch_bounds__(64) void finsum_kernel(const float* __restrict__ bpart,
                                                    float* __restrict__ out) {
    float v = threadIdx.x < 32 ? bpart[threadIdx.x] : 0.0f;
    #pragma unroll
    for (int off = 32; off; off >>= 1) v += __shfl_xor(v, off, 64);
    if (threadIdx.x == 0) out[0] = v / (float)N_SZ;
}

extern "C" void kernel_launch(void* const* d_in, const int* in_sizes, int n_in,
                              void* d_out, int out_size, void* d_ws, size_t ws_size,
                              hipStream_t stream) {
    const float* zi = (const float*)d_in[0];
    const float* zj = (const float*)d_in[1];

    char* ws = (char*)d_ws;
    char* znb      = ws;                                   // 2 MB fp8 k-seg layout
    float* pos     = (float*)(ws + 2097152);               // 32 KB
    float* partial = (float*)(ws + 2097152 + 32768);       // 32*8192*4 = 1 MB
    float* bpart   = (float*)(ws + 2097152 + 32768 + 1048576); // 128 B
    float* out = (float*)d_out;

    prep_kernel<<<B_SZ / 4, 256, 0, stream>>>(zi, zj, znb, pos);
    simlse_kernel<<<1024, 256, 0, stream>>>(znb, partial);
    rowsum_kernel<<<32, 256, 0, stream>>>(partial, pos, bpart);
    finsum_kernel<<<1, 64, 0, stream>>>(bpart, out);
}

// Round 7
// 37.366 us; speedup vs baseline: 1.4198x; 1.4198x over previous
//
#include <hip/hip_runtime.h>
#include <hip/hip_bf16.h>
#include <cmath>

#define B_SZ 4096
#define N_SZ 8192
#define D_SZ 256
#define EPS 1e-8f
// zn is stored as fp8 e4m3 scaled by 16 -> acc = 256*cos.
// exp(sim-2) with sim = 2*cos = acc/128:  exp2( acc*log2e/128 - 2*log2e )
#define EXPC 0.01127105500694503f      // log2(e)/128
#define EXPB -2.8853900817779268f      // -2*log2(e)

typedef __attribute__((ext_vector_type(4))) float f32x4;
typedef __attribute__((ext_vector_type(4))) int   i32x4;
typedef __attribute__((ext_vector_type(8))) int   i32x8;

// fp8 k-segment-transposed panel layout (1 byte/elem):
//   byte(row,k) = (row>>6)*16384 + (k>>4)*1024 + (row&63)*16 + (k&15)
// panel = 64 rows x 256 k = 16 KB. One K=128 MFMA operand (32 fp8) = two
// 16-B loads 1024 B apart.

// ---- Kernel 1: norms + pos (fp32 exact) + fp8 ZN. One wave per pair (i,i+B). ----
__global__ __launch_bounds__(256) void prep_kernel(const float* __restrict__ zi,
                                                   const float* __restrict__ zj,
                                                   char* __restrict__ znb,
                                                   float* __restrict__ pos) {
    const int wave = threadIdx.x >> 6, lane = threadIdx.x & 63;
    const int i = blockIdx.x * 4 + wave;               // 0..B-1
    float4 a = reinterpret_cast<const float4*>(zi + (size_t)i * D_SZ)[lane];
    float4 b = reinterpret_cast<const float4*>(zj + (size_t)i * D_SZ)[lane];
    float ssa = a.x * a.x + a.y * a.y + a.z * a.z + a.w * a.w;
    float ssb = b.x * b.x + b.y * b.y + b.z * b.z + b.w * b.w;
    float dab = a.x * b.x + a.y * b.y + a.z * b.z + a.w * b.w;
    #pragma unroll
    for (int off = 32; off; off >>= 1) {
        ssa += __shfl_xor(ssa, off, 64);
        ssb += __shfl_xor(ssb, off, 64);
        dab += __shfl_xor(dab, off, 64);
    }
    const float invna = 1.0f / fmaxf(sqrtf(ssa), EPS);
    const float invnb = 1.0f / fmaxf(sqrtf(ssb), EPS);
    if (lane == 0) {
        float p = dab * invna * invnb * 2.0f;
        pos[i] = p;
        pos[i + B_SZ] = p;
    }
    // lane covers k = 4*lane .. 4*lane+3; seg = lane>>2, in-seg byte = (lane&3)*4.
    const float sa = invna * 16.0f, sb = invnb * 16.0f;
    const int koff = (lane >> 2) * 1024 + (lane & 3) * 4;
    {
        int pk = __builtin_amdgcn_cvt_pk_fp8_f32(a.x * sa, a.y * sa, 0, false);
        pk     = __builtin_amdgcn_cvt_pk_fp8_f32(a.z * sa, a.w * sa, pk, true);
        *reinterpret_cast<int*>(znb + (size_t)(i >> 6) * 16384 + koff + (i & 63) * 16) = pk;
    }
    {
        const int r = i + B_SZ;
        int pk = __builtin_amdgcn_cvt_pk_fp8_f32(b.x * sb, b.y * sb, 0, false);
        pk     = __builtin_amdgcn_cvt_pk_fp8_f32(b.z * sb, b.w * sb, pk, true);
        *reinterpret_cast<int*>(znb + (size_t)(r >> 6) * 16384 + koff + (r & 63) * 16) = pk;
    }
}

// ---- Kernel 2: barrier-free fused fp8 K=128 sim-GEMM + fixed-base exp-sum ----
// Grid: 32 row-tiles x 32 j-chunks = 1024 blocks (4/CU), 256 thr (4 waves).
// NO LDS, NO __syncthreads: wave holds 64-row A panel in regs and streams B
// fragments straight from global (L2-resident 2 MB znb), 1-deep prefetch.
__global__ __launch_bounds__(256, 3) void simlse_kernel(const char* __restrict__ znb,
                                                        float* __restrict__ partial) {
    const int t = threadIdx.x;
    const int wave = t >> 6, lane = t & 63;
    const int rt = blockIdx.x >> 5;              // row tile 0..31 (256 rows)
    const int chunk = blockIdx.x & 31;           // j chunk 0..31 (256 cols)
    const int rl = lane & 15;                    // A-row / B-col within fragment
    const int kg = lane >> 4;                    // 32-elem k-block index
    const int i0 = rt * 256 + wave * 64;         // wave's first row

    // A panel: 4 rowgroups x 2 k-chunks of 128; 8 dwords (32 fp8) per frag.
    const char* ap = znb + (size_t)(rt * 4 + wave) * 16384 + rl * 16;
    i32x8 afrag[4][2];
    #pragma unroll
    for (int g = 0; g < 4; ++g)
        #pragma unroll
        for (int kc = 0; kc < 2; ++kc) {
            i32x4 lo = *reinterpret_cast<const i32x4*>(
                ap + (kc * 8 + kg * 2) * 1024 + g * 256);
            i32x4 hi = *reinterpret_cast<const i32x4*>(
                ap + (kc * 8 + kg * 2 + 1) * 1024 + g * 256);
            afrag[g][kc] = __builtin_shufflevector(lo, hi, 0, 1, 2, 3, 4, 5, 6, 7);
        }

    float s_acc[4][4];
    #pragma unroll
    for (int g = 0; g < 4; ++g)
        #pragma unroll
        for (int r = 0; r < 4; ++r) s_acc[g][r] = 0.0f;

    // B fragment base for this lane; per f-group of 16 cols:
    //   addr = bp0 + (f>>2)*16384 + (f&3)*256  (+8192 for kc=1, +1024 for hi half)
    const char* bp0 = znb + (size_t)chunk * 4 * 16384 + kg * 2048 + rl * 16;

    i32x4 nb0 = *reinterpret_cast<const i32x4*>(bp0);
    i32x4 nb1 = *reinterpret_cast<const i32x4*>(bp0 + 1024);
    i32x4 nb2 = *reinterpret_cast<const i32x4*>(bp0 + 8192);
    i32x4 nb3 = *reinterpret_cast<const i32x4*>(bp0 + 9216);

    #pragma unroll 1
    for (int f = 0; f < 16; ++f) {
        i32x8 bf0 = __builtin_shufflevector(nb0, nb1, 0, 1, 2, 3, 4, 5, 6, 7);
        i32x8 bf1 = __builtin_shufflevector(nb2, nb3, 0, 1, 2, 3, 4, 5, 6, 7);
        if (f < 15) {                           // prefetch next f-group
            const char* bq = bp0 + ((f + 1) >> 2) * 16384 + ((f + 1) & 3) * 256;
            nb0 = *reinterpret_cast<const i32x4*>(bq);
            nb1 = *reinterpret_cast<const i32x4*>(bq + 1024);
            nb2 = *reinterpret_cast<const i32x4*>(bq + 8192);
            nb3 = *reinterpret_cast<const i32x4*>(bq + 9216);
        }
        f32x4 acc[4];
        #pragma unroll
        for (int g = 0; g < 4; ++g) acc[g] = (f32x4){0.f, 0.f, 0.f, 0.f};
        #pragma unroll
        for (int g = 0; g < 4; ++g)             // kc0: 4 independent MFMAs
            asm("v_mfma_f32_16x16x128_f8f6f4 %0, %1, %2, %0"
                : "+v"(acc[g]) : "v"(afrag[g][0]), "v"(bf0));
        #pragma unroll
        for (int g = 0; g < 4; ++g)             // kc1: accumulate
            asm("v_mfma_f32_16x16x128_f8f6f4 %0, %1, %2, %0"
                : "+v"(acc[g]) : "v"(afrag[g][1]), "v"(bf1));
        asm volatile("s_nop 7");                // MFMA->VALU read hazard guard
        #pragma unroll
        for (int g = 0; g < 4; ++g)
            #pragma unroll
            for (int r = 0; r < 4; ++r)
                s_acc[g][r] += __builtin_amdgcn_exp2f(fmaf(acc[g][r], EXPC, EXPB));
    }

    // Sum over the 16 col-lanes (rl); rows i0 + g*16 + kg*4 + r.
    #pragma unroll
    for (int g = 0; g < 4; ++g)
        #pragma unroll
        for (int r = 0; r < 4; ++r) {
            float v = s_acc[g][r];
            #pragma unroll
            for (int off = 1; off < 16; off <<= 1) v += __shfl_xor(v, off, 64);
            if (rl == 0)
                partial[chunk * N_SZ + i0 + g * 16 + kg * 4 + r] = v;
        }
}

// ---- Kernel 3: per-row lse - pos, 32 block partials ----
__global__ __launch_bounds__(256) void rowsum_kernel(const float* __restrict__ partial,
                                                     const float* __restrict__ pos,
                                                     float* __restrict__ bpart) {
    const int row = blockIdx.x * 256 + threadIdx.x;
    float s = -1.0f;                       // remove diagonal exp(~0)=1
    #pragma unroll
    for (int c = 0; c < 32; ++c) s += partial[c * N_SZ + row];
    float acc = 2.0f + logf(s) - pos[row];
    #pragma unroll
    for (int off = 32; off; off >>= 1) acc += __shfl_xor(acc, off, 64);
    __shared__ float w[4];
    if ((threadIdx.x & 63) == 0) w[threadIdx.x >> 6] = acc;
    __syncthreads();
    if (threadIdx.x == 0) bpart[blockIdx.x] = w[0] + w[1] + w[2] + w[3];
}

__global__ __launch_bounds__(64) void finsum_kernel(const float* __restrict__ bpart,
                                                    float* __restrict__ out) {
    float v = threadIdx.x < 32 ? bpart[threadIdx.x] : 0.0f;
    #pragma unroll
    for (int off = 32; off; off >>= 1) v += __shfl_xor(v, off, 64);
    if (threadIdx.x == 0) out[0] = v / (float)N_SZ;
}

extern "C" void kernel_launch(void* const* d_in, const int* in_sizes, int n_in,
                              void* d_out, int out_size, void* d_ws, size_t ws_size,
                              hipStream_t stream) {
    const float* zi = (const float*)d_in[0];
    const float* zj = (const float*)d_in[1];

    char* ws = (char*)d_ws;
    char* znb      = ws;                                   // 2 MB fp8 k-seg layout
    float* pos     = (float*)(ws + 2097152);               // 32 KB
    float* partial = (float*)(ws + 2097152 + 32768);       // 32*8192*4 = 1 MB
    float* bpart   = (float*)(ws + 2097152 + 32768 + 1048576); // 128 B
    float* out = (float*)d_out;

    prep_kernel<<<B_SZ / 4, 256, 0, stream>>>(zi, zj, znb, pos);
    simlse_kernel<<<1024, 256, 0, stream>>>(znb, partial);
    rowsum_kernel<<<32, 256, 0, stream>>>(partial, pos, bpart);
    finsum_kernel<<<1, 64, 0, stream>>>(bpart, out);
}